// Round 5
// baseline (290.996 us; speedup 1.0000x reference)
//
#include <hip/hip_runtime.h>
#include <hip/hip_bf16.h>

// Problem: B=4,S=4096 tokens (16384), HIDDEN=1024, 16 heads x 64 dim.
// "Attention" mixes HEADS per token (16x16 softmax over heads), not sequence.
// Inputs/output fp32; compute bf16-MFMA w/ fp32 accumulate.
//
// R9 -> R10 (R9: 290.7us; QKV 124us, MfmaUtil 34.5%, 1 block/CU (128KB LDS)
// -> ~6200 cy/tile vs ~620 cy MFMA issue: per-phase serial sections dominate;
// sync-flavor variants measured equal, so reduce PHASE COUNT):
//  GEMM: 2 phases/tile (was 4). PhA: read A0,B0,B1 (16 b128) -> mmq<0,0>,
//  <0,1>; PhB: read A1 (8 b128) -> mmq<1,1>,<1,0>. Same MFMA order ->
//  bitwise-same accumulation. Stages: PhA stages A1(t+1); PhB stages
//  A0,B0,B1(t+2). Ledger (2 loads/half, per-wave): end-PhA VMCNT(8) leaves
//  exactly {A0,B0,B1,A1}(t+1) -> A1(t) guaranteed for PhB; end-PhB VMCNT(8)
//  leaves {A1(t+1), t+2 batch} -> A0,B0,B1(t+1) guaranteed for next PhA.
//  WAR: every overwritten region's last read is >=1 barrier earlier.
//  4 barriers + 2 walls per tile instead of 8 + 4.
//  ATTN/cvt: byte-identical to R9 (one variable per round).

typedef __bf16 bf16;
typedef __attribute__((ext_vector_type(8))) __bf16 bf16x8;
typedef __attribute__((ext_vector_type(4))) float floatx4;

#define HIDDEN 1024
#define BM 128
#define BN 128
#define BK 32

#define FENCE() asm volatile("" ::: "memory")
#define BAR()                                                                  \
    do {                                                                       \
        FENCE();                                                               \
        __builtin_amdgcn_s_barrier();                                          \
        FENCE();                                                               \
    } while (0)
#define VMCNT(N) asm volatile("s_waitcnt vmcnt(" #N ")" ::: "memory")

__device__ __forceinline__ void async_load16(const bf16* g, bf16* lds) {
    __builtin_amdgcn_global_load_lds(
        (const __attribute__((address_space(1))) void*)g,
        (__attribute__((address_space(3))) void*)lds, 16, 0, 0);
}

__device__ __forceinline__ bf16x8 load8(const bf16* p) {
    return *(const bf16x8*)p;
}
__device__ __forceinline__ bf16x8 load8(const float* p) {
    floatx4 lo = *(const floatx4*)p;
    floatx4 hi = *(const floatx4*)(p + 4);
    bf16x8 r;
#pragma unroll
    for (int i = 0; i < 4; ++i) { r[i] = (bf16)lo[i]; r[i + 4] = (bf16)hi[i]; }
    return r;
}

// ---------- one-time fp32 -> bf16 conversion: x then packed wq|wk|wv|wo ----
__global__ __launch_bounds__(256) void cvt_all(
    const float* __restrict__ x,
    const float* __restrict__ wq, const float* __restrict__ wk,
    const float* __restrict__ wv, const float* __restrict__ wo,
    bf16* __restrict__ xb, bf16* __restrict__ wpk, int mh8)
{
    const int per = (HIDDEN * HIDDEN) / 8;   // 131072 chunks per weight
    int i = blockIdx.x * 256 + threadIdx.x;
    if (i < mh8) {
        *(bf16x8*)&xb[(size_t)i * 8] = load8(&x[(size_t)i * 8]);
    } else {
        int j = i - mh8;
        int wsel = j / per;
        int off  = (j - wsel * per) * 8;
        const float* s = wsel == 0 ? wq : wsel == 1 ? wk : wsel == 2 ? wv : wo;
        *(bf16x8*)&wpk[(size_t)j * 8] = load8(&s[off]);
    }
}

// ---------- 256^2 2-phase GEMM ------------------------------------------
// C[m,n] = sum_k A[m,k]*W[n,k]. 512 thr = 8 waves (2M x 4N), wave tile
// 128x64, acc[8][4] 16x16 frags. LDS 128KB: [dbuf2][half2][128x64] x {A,B}.

// stage one 16KB half-tile (2 x global_load_lds/thread, linear LDS dest,
// inverse-swizzled global source). S=64 for A-halves, S=32 for B-halves.
template <int S>
__device__ __forceinline__ void stage_half(const bf16* __restrict__ gbase,
                                           int ld, int kt, bf16* lhalf,
                                           int h, int tid) {
#pragma unroll
    for (int j = 0; j < 2; ++j) {
        const int ci = j * 512 + tid;
        const int rr = ci >> 3;
        const int cs = (ci & 7) ^ (rr & 7);
        const int gr = h * S + (rr & (S - 1)) + (rr >> (S == 64 ? 6 : 5)) * (2 * S);
        async_load16(&gbase[(size_t)gr * ld + kt + cs * 8], &lhalf[ci * 8]);
    }
}

// frag reads from a half (both k-chunks), swizzled: chunk=(kk*4+quad)^(col&7)
__device__ __forceinline__ void ld_a4(const bf16* h, int wm, int col, int quad,
                                      int cx, bf16x8* a) {
#pragma unroll
    for (int i = 0; i < 4; ++i) {
        const int rr = i * 16 + col + (wm << 6);
#pragma unroll
        for (int kk = 0; kk < 2; ++kk)
            a[i * 2 + kk] =
                *(const bf16x8*)&h[rr * 64 + (((kk << 2) + quad) ^ cx) * 8];
    }
}
__device__ __forceinline__ void ld_b2(const bf16* h, int wn, int col, int quad,
                                      int cx, bf16x8* b) {
#pragma unroll
    for (int j = 0; j < 2; ++j) {
        const int rr = j * 16 + col + (wn << 5);
#pragma unroll
        for (int kk = 0; kk < 2; ++kk)
            b[j * 2 + kk] =
                *(const bf16x8*)&h[rr * 64 + (((kk << 2) + quad) ^ cx) * 8];
    }
}

template <int H, int G>
__device__ __forceinline__ void mmq(floatx4 (&acc)[8][4], const bf16x8 (&a)[8],
                                    const bf16x8 (&bb)[4]) {
    __builtin_amdgcn_s_setprio(1);
#pragma unroll
    for (int i = 0; i < 4; ++i)
#pragma unroll
        for (int j = 0; j < 2; ++j)
#pragma unroll
            for (int kk = 0; kk < 2; ++kk)
                acc[H * 4 + i][G * 2 + j] =
                    __builtin_amdgcn_mfma_f32_16x16x32_bf16(
                        a[i * 2 + kk], bb[j * 2 + kk],
                        acc[H * 4 + i][G * 2 + j], 0, 0, 0);
    __builtin_amdgcn_s_setprio(0);
}

template <typename TC>
__global__ __launch_bounds__(512, 2) void gemm8p(
    const bf16* __restrict__ A, const bf16* __restrict__ W,
    TC* __restrict__ C, int K, int lda, int ldc)
{
    __shared__ __align__(16) bf16 sA[2][2][128 * 64];   // 64 KB
    __shared__ __align__(16) bf16 sB[2][2][128 * 64];   // 64 KB

    const int tid  = threadIdx.x;
    const int lane = tid & 63;
    const int w    = tid >> 6;       // 0..7
    const int wm   = w >> 2;         // 0..1
    const int wn   = w & 3;          // 0..3
    const int m0   = blockIdx.x * 256;
    const int n0   = blockIdx.y * 256;
    const int col  = lane & 15;
    const int quad = lane >> 4;
    const int cx   = col & 7;

    const bf16* Ab = A + (size_t)m0 * lda;
    const bf16* Wb = W + (size_t)n0 * K;

    floatx4 acc[8][4] = {};
    bf16x8 a[8], b0[4], b1[4];

    const int T = K / 64;

    // Prologue: tile0 {A0,B0,B1,A1} + tile1 {A0,B0,B1}  (14 loads/thread).
    // A1(1) is staged at PhA(0) per the steady-state schedule.
    stage_half<64>(Ab, lda, 0, sA[0][0], 0, tid);
    stage_half<32>(Wb, K,   0, sB[0][0], 0, tid);
    stage_half<32>(Wb, K,   0, sB[0][1], 1, tid);
    stage_half<64>(Ab, lda, 0, sA[0][1], 1, tid);
    if (T > 1) {
        stage_half<64>(Ab, lda, 64, sA[1][0], 0, tid);
        stage_half<32>(Wb, K,   64, sB[1][0], 0, tid);
        stage_half<32>(Wb, K,   64, sB[1][1], 1, tid);
        VMCNT(6);                    // first 8 done = tile0 complete
    } else {
        VMCNT(0);
    }
    BAR();

    for (int t = 0; t < T; ++t) {
        const int b   = t & 1;
        const int kt1 = (t + 1) * 64;
        const int kt2 = (t + 2) * 64;

        // PhA: reads A0(t) frags + B0(t) + B1(t); stages A1(t+1).
        // End wait leaves exactly {A0,B0,B1,A1}(t+1) outstanding -> all
        // older (incl. A1(t), staged at PhA(t-1)) complete for PhB.
        ld_a4(sA[b][0], wm, col, quad, cx, a);
        ld_b2(sB[b][0], wn, col, quad, cx, b0);
        ld_b2(sB[b][1], wn, col, quad, cx, b1);
        if (t + 1 < T) {
            stage_half<64>(Ab, lda, kt1, sA[b ^ 1][1], 1, tid);
            VMCNT(8);
        } else {
            VMCNT(0);
        }
        BAR();
        mmq<0, 0>(acc, a, b0);
        mmq<0, 1>(acc, a, b1);
        BAR();

        // PhB: reads A1(t) frags; stages A0,B0,B1(t+2) over tile-t regions
        // (all last-read in PhA(t), >=1 barrier ago). End wait leaves
        // {A1(t+1), t+2 batch} -> A0,B0,B1(t+1) complete for next PhA.
        ld_a4(sA[b][1], wm, col, quad, cx, a);
        if (t + 2 < T) {
            stage_half<64>(Ab, lda, kt2, sA[b][0], 0, tid);
            stage_half<32>(Wb, K,   kt2, sB[b][0], 0, tid);
            stage_half<32>(Wb, K,   kt2, sB[b][1], 1, tid);
            VMCNT(8);
        } else {
            VMCNT(0);                // t=T-2 drains A1(T-1); t=T-1 no-op
        }
        BAR();
        mmq<1, 1>(acc, a, b1);
        mmq<1, 0>(acc, a, b0);
        BAR();
    }

#pragma unroll
    for (int mi = 0; mi < 8; ++mi) {
#pragma unroll
        for (int r = 0; r < 4; ++r) {
            const int row = m0 + wm * 128 + mi * 16 + quad * 4 + r;
#pragma unroll
            for (int ni = 0; ni < 4; ++ni) {
                const int cc = n0 + wn * 64 + ni * 16 + col;
                C[(size_t)row * ldc + cc] = (TC)acc[mi][ni][r];
            }
        }
    }
}

// ---------- R3 fallback GEMM (fp32-or-bf16 in, register staging) ----------
template <typename TA, typename TB, typename TC>
__global__ __launch_bounds__(256, 2) void gemm_bt(
    const TA* __restrict__ A, const TB* __restrict__ W,
    TC* __restrict__ C, int M, int N, int K)
{
    __shared__ __align__(16) bf16 sA[BM * BK];
    __shared__ __align__(16) bf16 sB[BN * BK];

    const int tid  = threadIdx.x;
    const int lane = tid & 63;
    const int w    = tid >> 6;
    const int wm   = w >> 1;
    const int wn   = w & 1;
    const int m0   = blockIdx.x * BM;
    const int n0   = blockIdx.y * BN;
    const int col  = lane & 15;
    const int quad = lane >> 4;

    floatx4 acc[4][4] = {};

    for (int kt = 0; kt < K; kt += BK) {
        bf16x8 ga[2], gb[2];
#pragma unroll
        for (int i = 0; i < 2; ++i) {
            const int c   = i * 256 + tid;
            const int row = c >> 2;
            const int kc  = c & 3;
            ga[i] = load8(&A[(size_t)(m0 + row) * K + kt + kc * 8]);
            gb[i] = load8(&W[(size_t)(n0 + row) * K + kt + kc * 8]);
        }
        __syncthreads();
#pragma unroll
        for (int i = 0; i < 2; ++i) {
            const int c = i * 256 + tid;
            *(bf16x8*)&sA[c * 8] = ga[i];
            *(bf16x8*)&sB[c * 8] = gb[i];
        }
        __syncthreads();

        bf16x8 af[4], bfr[4];
#pragma unroll
        for (int mi = 0; mi < 4; ++mi)
            af[mi] = *(const bf16x8*)&sA[(wm * 64 + mi * 16 + col) * BK + quad * 8];
#pragma unroll
        for (int ni = 0; ni < 4; ++ni)
            bfr[ni] = *(const bf16x8*)&sB[(wn * 64 + ni * 16 + col) * BK + quad * 8];

#pragma unroll
        for (int mi = 0; mi < 4; ++mi)
#pragma unroll
            for (int ni = 0; ni < 4; ++ni)
                acc[mi][ni] = __builtin_amdgcn_mfma_f32_16x16x32_bf16(
                    af[mi], bfr[ni], acc[mi][ni], 0, 0, 0);
    }

#pragma unroll
    for (int mi = 0; mi < 4; ++mi) {
#pragma unroll
        for (int r = 0; r < 4; ++r) {
            const int row = m0 + wm * 64 + mi * 16 + quad * 4 + r;
#pragma unroll
            for (int ni = 0; ni < 4; ++ni) {
                const int cc = n0 + wn * 64 + ni * 16 + col;
                C[(size_t)row * N + cc] = (TC)acc[mi][ni][r];
            }
        }
    }
}

// ---------- per-token head-mixing attention (R9, unchanged) --------------
// One wave per token. qkv row staged to LDS via global_load_lds (swizzled
// source, linear dest = wave-uniform + lane*16); per-wave vmcnt; NO barriers.
__global__ __launch_bounds__(256) void attn_heads(
    bf16* base, size_t koff, size_t voff, int stride, bf16* ob)
{
    __shared__ __align__(16) bf16 sQ[4][3072];       // [wave] q|k|v, 48x64
    __shared__ __align__(16) bf16 sP[4][16 * 40];    // [wave] P, pad-40 rows
    __shared__ __align__(16) bf16 sO[4][1024];       // [wave] O-tile, 8B swz

    const int tid   = threadIdx.x;
    const int lane  = tid & 63;
    const int w     = tid >> 6;
    const int token = blockIdx.x * 4 + w;
    const int col   = lane & 15;
    const int quad  = lane >> 4;

    bf16* qt = base + (size_t)token * stride;
    const bf16* src0 = qt;
    const bf16* src1 = qt + koff;
    const bf16* src2 = qt + voff;
    bf16* ot = ob + (size_t)token * HIDDEN;

    // Stage 6KB: rows 0..15 = Q[h][d], 16..31 = K, 32..47 = V (64-elem rows,
    // phys chunk c holds global chunk c^(row&7); source pre-swizzled).
#pragma unroll
    for (int i = 0; i < 6; ++i) {
        const int ci = i * 64 + lane;              // linear 16B chunk 0..383
        const int rl = (ci >> 3) & 15;             // row within region
        const int cs = (ci & 7) ^ (rl & 7);
        const bf16* s = (i < 2) ? src0 : (i < 4) ? src1 : src2;
        async_load16(&s[(rl * 8 + cs) * 8], &sQ[w][ci * 8]);
    }
    VMCNT(0);

    // S = Q K^T : conflict-free swizzled b128 frag reads.
    bf16x8 qa[2], kb[2];
#pragma unroll
    for (int kk = 0; kk < 2; ++kk) {
        const int c = ((kk << 2) + quad) ^ (col & 7);
        qa[kk] = *(const bf16x8*)&sQ[w][(col * 8 + c) * 8];
        kb[kk] = *(const bf16x8*)&sQ[w][((16 + col) * 8 + c) * 8];
    }
    floatx4 s = {};
    s = __builtin_amdgcn_mfma_f32_16x16x32_bf16(qa[0], kb[0], s, 0, 0, 0);
    s = __builtin_amdgcn_mfma_f32_16x16x32_bf16(qa[1], kb[1], s, 0, 0, 0);

    // PV A-frag (operand swap): va[dt][j] = V[g=quad*8+j][d=dt*16+col],
    // quad>=2 is k-padding (zeros both sides).
    bf16x8 va[4] = {};
    if (quad < 2) {
#pragma unroll
        for (int dt = 0; dt < 4; ++dt) {
            const int cb = dt * 2 + (col >> 3);
#pragma unroll
            for (int j = 0; j < 8; ++j) {
                const int r = 32 + quad * 8 + j;
                va[dt][j] = sQ[w][(r * 8 + (cb ^ j)) * 8 + (col & 7)];
            }
        }
    }

    // Max-free softmax over g (S/8 ~ N(0,1); fp32-safe).
#pragma unroll
    for (int r = 0; r < 4; ++r) {
        float e = __expf(s[r] * 0.125f);
        float su = e;
#pragma unroll
        for (int off = 1; off < 16; off <<= 1)
            su += __shfl_xor(su, off);
        sP[w][(quad * 4 + r) * 40 + col] = (bf16)(e / su);
    }

    // O = P V with swap: D -> O[h=col][d=dt*16+quad*4+r] (d-contiguous).
    bf16x8 pa = {};
    if (quad < 2) pa = *(const bf16x8*)&sP[w][col * 40 + quad * 8];
#pragma unroll
    for (int dt = 0; dt < 4; ++dt) {
        floatx4 o4 = {};
        o4 = __builtin_amdgcn_mfma_f32_16x16x32_bf16(va[dt], pa, o4, 0, 0, 0);
        union { bf16 h4[4]; uint2 u; } pk;
#pragma unroll
        for (int r = 0; r < 4; ++r) pk.h4[r] = (bf16)o4[r];
        const int c8 = dt * 4 + quad;
        *(uint2*)&sO[w][(col * 16 + (c8 ^ col)) * 4] = pk.u;
    }

    // Coalesced O out: 4 x (64 lanes x 8B) = 512B runs.
#pragma unroll
    for (int it = 0; it < 4; ++it) {
        const int n8 = it * 64 + lane;
        const int h = n8 >> 4, c8 = n8 & 15;
        const uint2 d = *(const uint2*)&sO[w][(h * 16 + (c8 ^ h)) * 4];
        *(uint2*)&ot[n8 * 4] = d;
    }
}

extern "C" void kernel_launch(void* const* d_in, const int* in_sizes, int n_in,
                              void* d_out, int out_size, void* d_ws, size_t ws_size,
                              hipStream_t stream) {
    const float* x  = (const float*)d_in[0];
    const float* wq = (const float*)d_in[1];
    const float* wk = (const float*)d_in[2];
    const float* wv = (const float*)d_in[3];
    const float* wo = (const float*)d_in[4];
    float* out = (float*)d_out;

    const int M = in_sizes[0] / HIDDEN;   // 16384 tokens
    const size_t MH = (size_t)M * HIDDEN;
    const size_t WH = (size_t)HIDDEN * HIDDEN;

    const size_t need = (MH + 4 * WH + (size_t)M * 3 * HIDDEN) * sizeof(bf16);

    if (ws_size >= need && (M % 256) == 0) {
        // Fast path: convert once, 2-phase bf16 GEMMs.
        bf16* xb  = (bf16*)d_ws;          // [M][1024]; reused as O after QKV
        bf16* wpk = xb + MH;              // [4][1024][1024] packed q|k|v|o
        bf16* qkv = wpk + 4 * WH;         // [M][3072]

        const int mh8 = (int)(MH / 8);
        const int nchunks = mh8 + (int)(4 * WH / 8);
        cvt_all<<<dim3(nchunks / 256), 256, 0, stream>>>(x, wq, wk, wv, wo,
                                                         xb, wpk, mh8);

        gemm8p<bf16><<<dim3(M / 256, 3 * HIDDEN / 256), 512, 0, stream>>>(
            xb, wpk, qkv, HIDDEN, HIDDEN, 3 * HIDDEN);

        // xb is dead now; attn writes O into it (dense lda=1024 for Wo GEMM).
        attn_heads<<<dim3(M / 4), 256, 0, stream>>>(qkv, 1024, 2048,
                                                    3 * HIDDEN, xb);

        gemm8p<float><<<dim3(M / 256, HIDDEN / 256), 512, 0, stream>>>(
            xb, wpk + 3 * WH, out, HIDDEN, HIDDEN, HIDDEN);
    } else {
        // R3 proven fallback (needs 100.7 MB).
        bf16* qb = (bf16*)d_ws;
        bf16* kb = qb + MH;
        bf16* vb = kb + MH;
        dim3 grid(M / BM, HIDDEN / BN), block(256);
        gemm_bt<float, float, bf16><<<grid, block, 0, stream>>>(x, wq, qb, M, HIDDEN, HIDDEN);
        gemm_bt<float, float, bf16><<<grid, block, 0, stream>>>(x, wk, kb, M, HIDDEN, HIDDEN);
        gemm_bt<float, float, bf16><<<grid, block, 0, stream>>>(x, wv, vb, M, HIDDEN, HIDDEN);
        attn_heads<<<dim3(M / 4), block, 0, stream>>>(qb, MH, 2 * MH, HIDDEN, qb);
        gemm_bt<bf16, float, float><<<grid, block, 0, stream>>>(qb, wo, out, M, HIDDEN, HIDDEN);
    }
}